// Round 4
// baseline (472.819 us; speedup 1.0000x reference)
//
#include <hip/hip_runtime.h>
#include <stdint.h>

// SAGEConv: out = concat([x, mean_neigh(x)]) @ W.T + b
// N=100000, MAX_DEG=16, D_IN=256, D_OUT=256
//
// R4: decoupled pipeline. K1 casts x/W to bf16 (zero row at idx N for pads).
// K2 = pure gather/aggregate, no LDS, no barriers: each thread owns one 16B
// output chunk, stages all 16 neighbor loads (sched_barrier pins the group),
// 62% occupancy with ~100 VGPRs -> max memory-level parallelism.
// K3 = GEMM out = [Xb|Agg] @ W^T + b, A-frags straight from global (L1-resident
// 32KB/block tile), B from L2, no LDS at all.

#define MAX_DEG 16
#define D_IN 256
#define D_K 512
#define D_OUT 256
#define N_NODES_C 100000
#define LDS_STRIDE 520   // fused-fallback only

typedef __attribute__((ext_vector_type(8))) short bf16x8;   // 8 bf16 = 4 VGPRs
typedef __attribute__((ext_vector_type(4))) float f32x4;

__device__ __forceinline__ uint32_t f2bf(float f) {
    union { float f; uint32_t u; } v; v.f = f;
    uint32_t u = v.u;
    return (u + 0x7FFFu + ((u >> 16) & 1u)) >> 16;   // RNE; inputs finite
}
__device__ __forceinline__ uint32_t pack2(float lo, float hi) {
    return f2bf(lo) | (f2bf(hi) << 16);
}

// ---- K1: cast x (+ zero row at index N) and W to bf16 in ws ----
__global__ __launch_bounds__(256) void cast_all_kernel(
    const float* __restrict__ x, const float* __restrict__ W,
    ushort* __restrict__ Xb, ushort* __restrict__ Wb)
{
    const int b = blockIdx.x;
    const int tid = threadIdx.x;
    if (b < 12500) {
        const size_t i = (size_t)b * 2048 + tid * 8;
        float4 v0 = *(const float4*)(x + i);
        float4 v1 = *(const float4*)(x + i + 4);
        uint4 p = { pack2(v0.x, v0.y), pack2(v0.z, v0.w),
                    pack2(v1.x, v1.y), pack2(v1.z, v1.w) };
        *(uint4*)(Xb + i) = p;
    } else if (b == 12500) {
        if (tid < 32) {
            uint4 z = {0u, 0u, 0u, 0u};
            *(uint4*)(Xb + (size_t)N_NODES_C * D_IN + tid * 8) = z;
        }
    } else {
        const size_t i = (size_t)(b - 12501) * 2048 + tid * 8;
        float4 v0 = *(const float4*)(W + i);
        float4 v1 = *(const float4*)(W + i + 4);
        uint4 p = { pack2(v0.x, v0.y), pack2(v0.z, v0.w),
                    pack2(v1.x, v1.y), pack2(v1.z, v1.w) };
        *(uint4*)(Wb + i) = p;
    }
}

// ---- K2: gather + mean-aggregate, no LDS, no barriers ----
// thread t -> (node = t>>5, 16B chunk c = t&31). 16 staged 16B gathers.
__global__ __launch_bounds__(256, 5) void gather_kernel(
    const ushort* __restrict__ Xb,     // [N+1][D_IN] bf16, row N = zeros
    const int* __restrict__ edge,
    ushort* __restrict__ Agg)          // [N][D_IN] bf16 mean-neighbor
{
    const int t = blockIdx.x * 256 + threadIdx.x;
    const int node = t >> 5;
    const int c = t & 31;

    const int4* ep = (const int4*)(edge + (size_t)node * MAX_DEG);
    uint32_t off[MAX_DEG]; int deg = 0;
    #pragma unroll
    for (int g = 0; g < 4; ++g) {
        int4 e = ep[g];
        deg += (e.x >= 0) + (e.y >= 0) + (e.z >= 0) + (e.w >= 0);
        off[g*4+0] = (uint32_t)(e.x < 0 ? N_NODES_C : e.x) * 512u;
        off[g*4+1] = (uint32_t)(e.y < 0 ? N_NODES_C : e.y) * 512u;
        off[g*4+2] = (uint32_t)(e.z < 0 ? N_NODES_C : e.z) * 512u;
        off[g*4+3] = (uint32_t)(e.w < 0 ? N_NODES_C : e.w) * 512u;
    }

    // lanes c=0..31 of one node cover a contiguous 512B row: full-line bursts
    const char* base = (const char*)Xb + c * 16;
    uint4 st[MAX_DEG];
    #pragma unroll
    for (int d = 0; d < MAX_DEG; ++d)
        st[d] = *(const uint4*)(base + (size_t)off[d]);
#if defined(__has_builtin)
#if __has_builtin(__builtin_amdgcn_sched_barrier)
    __builtin_amdgcn_sched_barrier(0);   // keep all 16 loads issued before use
#endif
#endif

    float a[8];
    #pragma unroll
    for (int q = 0; q < 8; ++q) a[q] = 0.f;
    #pragma unroll
    for (int d = 0; d < MAX_DEG; ++d) {
        uint32_t u[4] = { st[d].x, st[d].y, st[d].z, st[d].w };
        #pragma unroll
        for (int q = 0; q < 4; ++q) {
            union { uint32_t ui; float f; } lo, hi;
            lo.ui = u[q] << 16;
            hi.ui = u[q] & 0xFFFF0000u;
            a[2*q]   += lo.f;
            a[2*q+1] += hi.f;
        }
    }
    const float inv = 1.0f / (float)deg;   // deg >= 1
    uint4 p = { pack2(a[0]*inv, a[1]*inv), pack2(a[2]*inv, a[3]*inv),
                pack2(a[4]*inv, a[5]*inv), pack2(a[6]*inv, a[7]*inv) };
    *(uint4*)(Agg + (size_t)node * D_IN + c * 8) = p;
}

// ---- K3: out[32-node tile, 256] = [Xb|Agg] @ W^T + b, no LDS ----
// 8 waves/block: wave w = 32-col eighth, covers both 16-row strips.
__global__ __launch_bounds__(512) void gemm_kernel(
    const ushort* __restrict__ Xb,
    const ushort* __restrict__ Agg,
    const ushort* __restrict__ Wb,     // [D_OUT][D_K] bf16
    const float* __restrict__ bias,
    float* __restrict__ out)
{
    const int tid = threadIdx.x;
    const int node0 = blockIdx.x * 32;
    const int w = tid >> 6;
    const int lane = tid & 63;
    const int quad = lane >> 4;
    const int r16  = lane & 15;

    f32x4 acc[2][2];
    #pragma unroll
    for (int j = 0; j < 2; ++j) {
        float bv = bias[w * 32 + j * 16 + r16];   // D col = lane&15
        acc[0][j] = (f32x4){bv, bv, bv, bv};
        acc[1][j] = (f32x4){bv, bv, bv, bv};
    }

    // A-frag: A[m=r16][k=quad*8+j], rows node0+strip*16+r16
    const ushort* x0 = Xb  + (size_t)(node0 + r16) * D_IN + quad * 8;
    const ushort* x1 = x0 + 16 * D_IN;
    const ushort* g0 = Agg + (size_t)(node0 + r16) * D_IN + quad * 8;
    const ushort* g1 = g0 + 16 * D_IN;

    #pragma unroll
    for (int ks = 0; ks < 8; ++ks) {          // self half: k in [0,256)
        bf16x8 a0 = *(const bf16x8*)(x0 + ks * 32);
        bf16x8 a1 = *(const bf16x8*)(x1 + ks * 32);
        #pragma unroll
        for (int j = 0; j < 2; ++j) {
            const int o = w * 32 + j * 16 + r16;
            bf16x8 b = *(const bf16x8*)(Wb + (size_t)o * D_K + ks * 32 + quad * 8);
            acc[0][j] = __builtin_amdgcn_mfma_f32_16x16x32_bf16(a0, b, acc[0][j], 0, 0, 0);
            acc[1][j] = __builtin_amdgcn_mfma_f32_16x16x32_bf16(a1, b, acc[1][j], 0, 0, 0);
        }
    }
    #pragma unroll
    for (int ks = 0; ks < 8; ++ks) {          // neighbor half: k in [256,512)
        bf16x8 a0 = *(const bf16x8*)(g0 + ks * 32);
        bf16x8 a1 = *(const bf16x8*)(g1 + ks * 32);
        #pragma unroll
        for (int j = 0; j < 2; ++j) {
            const int o = w * 32 + j * 16 + r16;
            bf16x8 b = *(const bf16x8*)(Wb + (size_t)o * D_K + (8 + ks) * 32 + quad * 8);
            acc[0][j] = __builtin_amdgcn_mfma_f32_16x16x32_bf16(a0, b, acc[0][j], 0, 0, 0);
            acc[1][j] = __builtin_amdgcn_mfma_f32_16x16x32_bf16(a1, b, acc[1][j], 0, 0, 0);
        }
    }

    // D layout: col = lane&15, row = quad*4 + reg
    #pragma unroll
    for (int mt = 0; mt < 2; ++mt) {
        #pragma unroll
        for (int j = 0; j < 2; ++j) {
            const int o = w * 32 + j * 16 + r16;
            #pragma unroll
            for (int r = 0; r < 4; ++r) {
                const int row = node0 + mt * 16 + quad * 4 + r;
                out[(size_t)row * D_OUT + o] = acc[mt][j][r];
            }
        }
    }
}

// ================= fallback 1 (ws >= 51.5MB): R3 fused path =================
__global__ __launch_bounds__(512, 4) void sage_bf16_kernel(
    const ushort* __restrict__ Xb, const int* __restrict__ edge,
    const ushort* __restrict__ Wb, const float* __restrict__ bias,
    float* __restrict__ out)
{
    __shared__ ushort sH[32 * LDS_STRIDE];
    const int tid = threadIdx.x;
    const int node0 = blockIdx.x * 32;
    {
        const int m = tid >> 4, l = tid & 15;
        const int node = node0 + m;
        const uint4* xr = (const uint4*)(Xb + (size_t)node * D_IN);
        uint4* selfdst = (uint4*)(sH + (size_t)m * LDS_STRIDE);
        uint4 s0 = xr[l], s1 = xr[16 + l];
        selfdst[l] = s0; selfdst[16 + l] = s1;

        const int4* ep = (const int4*)(edge + (size_t)node * MAX_DEG);
        uint32_t off[MAX_DEG]; int deg = 0;
        #pragma unroll
        for (int g = 0; g < 4; ++g) {
            int4 e = ep[g];
            deg += (e.x >= 0) + (e.y >= 0) + (e.z >= 0) + (e.w >= 0);
            off[g*4+0] = (uint32_t)(e.x < 0 ? N_NODES_C : e.x) * 512u;
            off[g*4+1] = (uint32_t)(e.y < 0 ? N_NODES_C : e.y) * 512u;
            off[g*4+2] = (uint32_t)(e.z < 0 ? N_NODES_C : e.z) * 512u;
            off[g*4+3] = (uint32_t)(e.w < 0 ? N_NODES_C : e.w) * 512u;
        }
        const float inv = 1.0f / (float)deg;
        const char* xb = (const char*)Xb;
        #pragma unroll 1
        for (int c = 0; c < 2; ++c) {
            const uint32_t coff = (uint32_t)(c * 256 + l * 16);
            uint4 st[MAX_DEG];
            #pragma unroll
            for (int d = 0; d < MAX_DEG; ++d)
                st[d] = *(const uint4*)(xb + (size_t)(off[d] + coff));
            float a[8];
            #pragma unroll
            for (int q = 0; q < 8; ++q) a[q] = 0.f;
            #pragma unroll
            for (int d = 0; d < MAX_DEG; ++d) {
                uint32_t u[4] = { st[d].x, st[d].y, st[d].z, st[d].w };
                #pragma unroll
                for (int q = 0; q < 4; ++q) {
                    union { uint32_t ui; float f; } lo, hi;
                    lo.ui = u[q] << 16;
                    hi.ui = u[q] & 0xFFFF0000u;
                    a[2*q]   += lo.f;
                    a[2*q+1] += hi.f;
                }
            }
            uint4 p = { pack2(a[0]*inv, a[1]*inv), pack2(a[2]*inv, a[3]*inv),
                        pack2(a[4]*inv, a[5]*inv), pack2(a[6]*inv, a[7]*inv) };
            *(uint4*)(sH + (size_t)m * LDS_STRIDE + D_IN + c * 128 + l * 8) = p;
        }
    }
    __syncthreads();
    {
        const int w = tid >> 6, lane = tid & 63;
        const int quad = lane >> 4, r16 = lane & 15;
        f32x4 acc[2][2];
        #pragma unroll
        for (int j = 0; j < 2; ++j) {
            float bv = bias[w * 32 + j * 16 + r16];
            acc[0][j] = (f32x4){bv, bv, bv, bv};
            acc[1][j] = (f32x4){bv, bv, bv, bv};
        }
        const ushort* a0p = sH + (size_t)r16 * LDS_STRIDE + quad * 8;
        const ushort* a1p = a0p + 16 * LDS_STRIDE;
        #pragma unroll
        for (int ks = 0; ks < D_K / 32; ++ks) {
            bf16x8 a0 = *(const bf16x8*)(a0p + ks * 32);
            bf16x8 a1 = *(const bf16x8*)(a1p + ks * 32);
            #pragma unroll
            for (int j = 0; j < 2; ++j) {
                const int o = w * 32 + j * 16 + r16;
                bf16x8 b = *(const bf16x8*)(Wb + (size_t)o * D_K + ks * 32 + quad * 8);
                acc[0][j] = __builtin_amdgcn_mfma_f32_16x16x32_bf16(a0, b, acc[0][j], 0, 0, 0);
                acc[1][j] = __builtin_amdgcn_mfma_f32_16x16x32_bf16(a1, b, acc[1][j], 0, 0, 0);
            }
        }
        #pragma unroll
        for (int mt = 0; mt < 2; ++mt) {
            #pragma unroll
            for (int j = 0; j < 2; ++j) {
                const int o = w * 32 + j * 16 + r16;
                #pragma unroll
                for (int r = 0; r < 4; ++r) {
                    const int row = node0 + mt * 16 + quad * 4 + r;
                    out[(size_t)row * D_OUT + o] = acc[mt][j][r];
                }
            }
        }
    }
}

// ================= fallback 2 (tiny ws): fp32-gather path =================
__global__ __launch_bounds__(256) void cast_w_kernel(const float* __restrict__ W,
                                                     ushort* __restrict__ Wb) {
    int i = (blockIdx.x * 256 + threadIdx.x) * 4;
    float4 v = *(const float4*)(W + i);
    ushort4 p = { (ushort)f2bf(v.x), (ushort)f2bf(v.y),
                  (ushort)f2bf(v.z), (ushort)f2bf(v.w) };
    *(ushort4*)(Wb + i) = p;
}

__global__ __launch_bounds__(256) void sage_fp32_kernel(
    const float* __restrict__ x, const int* __restrict__ edge,
    const ushort* __restrict__ Wb, const float* __restrict__ bias,
    float* __restrict__ out)
{
    __shared__ ushort sH[32 * LDS_STRIDE];
    const int tid = threadIdx.x;
    const int node0 = blockIdx.x * 32;
    {
        const int m = tid >> 3, l = tid & 7;
        const int node = node0 + m;
        const float4* xrow = (const float4*)(x + (size_t)node * D_IN);
        ushort* dst = sH + m * LDS_STRIDE + l * 32;
        #pragma unroll
        for (int q = 0; q < 8; ++q) {
            float4 v = xrow[l * 8 + q];
            ushort4 p = { (ushort)f2bf(v.x), (ushort)f2bf(v.y),
                          (ushort)f2bf(v.z), (ushort)f2bf(v.w) };
            *(ushort4*)(dst + q * 4) = p;
        }
        float4 agg[8];
        #pragma unroll
        for (int q = 0; q < 8; ++q) agg[q] = make_float4(0.f,0.f,0.f,0.f);
        int deg = 0;
        for (int d = 0; d < MAX_DEG; ++d) {
            int nb = edge[(size_t)node * MAX_DEG + d];
            if (nb >= 0) {
                ++deg;
                const float4* nr = (const float4*)(x + (size_t)nb * D_IN);
                #pragma unroll
                for (int q = 0; q < 8; ++q) {
                    float4 t = nr[l * 8 + q];
                    agg[q].x += t.x; agg[q].y += t.y;
                    agg[q].z += t.z; agg[q].w += t.w;
                }
            }
        }
        const float inv = 1.0f / (float)deg;
        ushort* dst2 = sH + m * LDS_STRIDE + D_IN + l * 32;
        #pragma unroll
        for (int q = 0; q < 8; ++q) {
            ushort4 p = { (ushort)f2bf(agg[q].x*inv), (ushort)f2bf(agg[q].y*inv),
                          (ushort)f2bf(agg[q].z*inv), (ushort)f2bf(agg[q].w*inv) };
            *(ushort4*)(dst2 + q * 4) = p;
        }
    }
    __syncthreads();
    {
        const int wave = tid >> 6, lane = tid & 63;
        const int quad = lane >> 4, r16 = lane & 15;
        const int mt = wave & 1, nh = wave >> 1;
        f32x4 acc[8];
        #pragma unroll
        for (int j = 0; j < 8; ++j) {
            float bv = bias[(nh * 8 + j) * 16 + r16];
            acc[j] = (f32x4){bv, bv, bv, bv};
        }
        const ushort* arow = sH + (mt * 16 + r16) * LDS_STRIDE + quad * 8;
        #pragma unroll
        for (int ks = 0; ks < D_K / 32; ++ks) {
            bf16x8 a = *(const bf16x8*)(arow + ks * 32);
            #pragma unroll
            for (int j = 0; j < 8; ++j) {
                const int o = (nh * 8 + j) * 16 + r16;
                bf16x8 b = *(const bf16x8*)(Wb + (size_t)o * D_K + ks * 32 + quad * 8);
                acc[j] = __builtin_amdgcn_mfma_f32_16x16x32_bf16(a, b, acc[j], 0, 0, 0);
            }
        }
        #pragma unroll
        for (int j = 0; j < 8; ++j) {
            const int o = (nh * 8 + j) * 16 + r16;
            #pragma unroll
            for (int r = 0; r < 4; ++r) {
                const int row = node0 + mt * 16 + quad * 4 + r;
                out[(size_t)row * D_OUT + o] = acc[j][r];
            }
        }
    }
}

extern "C" void kernel_launch(void* const* d_in, const int* in_sizes, int n_in,
                              void* d_out, int out_size, void* d_ws, size_t ws_size,
                              hipStream_t stream) {
    const float* x    = (const float*)d_in[0];
    const int*   edge = (const int*)d_in[1];
    const float* W    = (const float*)d_in[2];
    const float* bias = (const float*)d_in[3];
    float* out = (float*)d_out;

    const size_t xb_bytes  = (size_t)(N_NODES_C + 1) * D_IN * 2;  // 51,200,512
    const size_t wb_bytes  = (size_t)D_OUT * D_K * 2;             // 262,144
    const size_t agg_bytes = (size_t)N_NODES_C * D_IN * 2;        // 51,200,000
    const int n = in_sizes[0] / D_IN;                             // 100000

    if (ws_size >= xb_bytes + wb_bytes + agg_bytes) {
        ushort* Xb  = (ushort*)d_ws;
        ushort* Wb  = (ushort*)((char*)d_ws + xb_bytes);
        ushort* Agg = (ushort*)((char*)d_ws + xb_bytes + wb_bytes);
        cast_all_kernel<<<12565, 256, 0, stream>>>(x, W, Xb, Wb);
        gather_kernel<<<(n * 32) / 256, 256, 0, stream>>>(Xb, edge, Agg);
        gemm_kernel<<<n / 32, 512, 0, stream>>>(Xb, Agg, Wb, bias, out);
    } else if (ws_size >= xb_bytes + wb_bytes) {
        ushort* Xb = (ushort*)d_ws;
        ushort* Wb = (ushort*)((char*)d_ws + xb_bytes);
        cast_all_kernel<<<12565, 256, 0, stream>>>(x, W, Xb, Wb);
        sage_bf16_kernel<<<n / 32, 512, 0, stream>>>(Xb, edge, Wb, bias, out);
    } else {
        ushort* Wb = (ushort*)d_ws;
        cast_w_kernel<<<(D_OUT * D_K) / 1024, 256, 0, stream>>>(W, Wb);
        sage_fp32_kernel<<<n / 32, 256, 0, stream>>>(x, edge, Wb, bias, out);
    }
}